// Round 10
// baseline (326.808 us; speedup 1.0000x reference)
//
#include <hip/hip_runtime.h>

#define BATCH 2
#define SEQ 2048
#define EMBED 2048
#define NHEADS 32
#define NKV 8
#define HDIM 64
#define QKV_LD 3072  // fused [Q(2048) | K(512) | V(512)] row stride
#define LOG2E 1.44269504088896f

typedef __attribute__((ext_vector_type(8))) short short8;
typedef __attribute__((ext_vector_type(4))) float f32x4;

__device__ inline float hw_exp2(float x) { return __builtin_amdgcn_exp2f(x); }

__device__ inline ushort f2bf(float f) {
  union { float f; unsigned u; } v{f};
  unsigned r = v.u + 0x7FFF + ((v.u >> 16) & 1);
  return (ushort)(r >> 16);
}
__device__ inline float bf2f(ushort u) {
  union { unsigned u; float f; } v{((unsigned)u) << 16};
  return v.f;
}
__device__ inline unsigned fbits(float f) {
  union { float f; unsigned u; } v{f};
  return v.u;
}

__device__ inline void gload16(const ushort* g, ushort* l) {
  __builtin_amdgcn_global_load_lds(
      (const __attribute__((address_space(1))) unsigned*)g,
      (__attribute__((address_space(3))) unsigned*)l, 16, 0, 0);
}

#define PHASE_BAR()                          \
  do {                                       \
    __builtin_amdgcn_sched_barrier(0);       \
    __builtin_amdgcn_s_barrier();            \
    __builtin_amdgcn_sched_barrier(0);       \
  } while (0)

// ---------------- fused fp32 -> bf16 convert (all 5 tensors, 1 launch) ----------------
__global__ __launch_bounds__(256) void cvt_all(const float* __restrict__ x,
                                               const float* __restrict__ wq,
                                               const float* __restrict__ wk,
                                               const float* __restrict__ wv,
                                               const float* __restrict__ wo,
                                               ushort* __restrict__ xb,
                                               ushort* __restrict__ wqkv,
                                               ushort* __restrict__ wob) {
  size_t e = (size_t)(blockIdx.x * blockDim.x + threadIdx.x) * 8;
  const float* src;
  ushort* dst;
  if (e < 8388608u) { src = x + e; dst = xb + e; }
  else if (e < 12582912u) { size_t o = e - 8388608u; src = wq + o; dst = wqkv + o; }
  else if (e < 13631488u) { size_t o = e - 12582912u; src = wk + o; dst = wqkv + 4194304u + o; }
  else if (e < 14680064u) { size_t o = e - 13631488u; src = wv + o; dst = wqkv + 5242880u + o; }
  else { size_t o = e - 14680064u; src = wo + o; dst = wob + o; }
  float4 v0 = ((const float4*)src)[0];
  float4 v1 = ((const float4*)src)[1];
  union { uint4 v; ushort u[8]; } pk;
  pk.u[0] = f2bf(v0.x); pk.u[1] = f2bf(v0.y); pk.u[2] = f2bf(v0.z); pk.u[3] = f2bf(v0.w);
  pk.u[4] = f2bf(v1.x); pk.u[5] = f2bf(v1.y); pk.u[6] = f2bf(v1.z); pk.u[7] = f2bf(v1.w);
  *(uint4*)dst = pk.v;
}

// ---------------- 8-phase bf16 GEMM template: C[M,N] = A * B^T (v10, frozen) --------
template <int BN, int MODE, typename OutT>
__global__ __launch_bounds__(512) void gemm8p(const ushort* __restrict__ Ag,
                                              const ushort* __restrict__ Bg,
                                              OutT* __restrict__ C,
                                              const float* __restrict__ fc,
                                              const float* __restrict__ fs,
                                              int M, int N, int K) {
  constexpr int NF = BN / 64;  // per-wave 16-col fragments
  __shared__ ushort As[2][2][256][32];
  __shared__ ushort Bs[2][2][BN][32];
  const int tid = threadIdx.x;
  const int lane = tid & 63, wave = tid >> 6;
  const int quad = lane >> 4, l16 = lane & 15;
  const int wm = wave >> 2, wn = wave & 3;  // 2M x 4N
  const int m0 = blockIdx.y * 256, n0 = blockIdx.x * BN;
  const int NT = K >> 6;

  auto stA = [&](int Tn, int h) {
    const int r0 = h * 128 + wave * 16;
    const ushort* g = Ag + (size_t)(m0 + r0 + (lane >> 2)) * K + Tn * 64 + (lane & 3) * 8;
    gload16(g, &As[Tn & 1][0][r0][0]);
    gload16(g + 32, &As[Tn & 1][1][r0][0]);
  };
  auto stB = [&](int Tn, int h) {
    const int r0 = h * 128 + wave * 16;
    const ushort* g = Bg + (size_t)(n0 + r0 + (lane >> 2)) * K + Tn * 64 + (lane & 3) * 8;
    gload16(g, &Bs[Tn & 1][0][r0][0]);
    gload16(g + 32, &Bs[Tn & 1][1][r0][0]);
  };

  f32x4 acc[8][NF] = {};

  // prologue: stage K-tile 0 fully
  stA(0, 0); stA(0, 1);
  stB(0, 0);
  if constexpr (BN == 256) stB(0, 1);

  for (int T = 0; T < NT; ++T) {
    const int bf = T & 1;
    asm volatile("s_waitcnt vmcnt(0)" ::: "memory");
    PHASE_BAR();

    // B-frags for the whole K-tile (phase 0 reads)
    short8 bfr[NF][2];
#pragma unroll
    for (int nf = 0; nf < NF; nf++)
#pragma unroll
      for (int kk = 0; kk < 2; kk++)
        bfr[nf][kk] = *(short8*)&Bs[bf][kk][wn * (16 * NF) + nf * 16 + l16][quad * 8];

#pragma unroll
    for (int q = 0; q < 4; q++) {
      short8 afr[2][2];
#pragma unroll
      for (int mq = 0; mq < 2; mq++)
#pragma unroll
        for (int kk = 0; kk < 2; kk++)
          afr[mq][kk] = *(short8*)&As[bf][kk][wm * 128 + (2 * q + mq) * 16 + l16][quad * 8];

      // per-phase staging of tile T+1 into the other buffer (v8 schedule)
      if (T + 1 < NT) {
        if (q == 0) stA(T + 1, 0);
        else if (q == 1) stA(T + 1, 1);
        else if (q == 2) stB(T + 1, 0);
        else if constexpr (BN == 256) stB(T + 1, 1);
      }

      __builtin_amdgcn_s_setprio(1);
#pragma unroll
      for (int mq = 0; mq < 2; mq++)
#pragma unroll
        for (int nf = 0; nf < NF; nf++)
#pragma unroll
          for (int kk = 0; kk < 2; kk++)
            acc[2 * q + mq][nf] = __builtin_amdgcn_mfma_f32_16x16x32_bf16(
                afr[mq][kk], bfr[nf][kk], acc[2 * q + mq][nf], 0, 0, 0);
      __builtin_amdgcn_s_setprio(0);
      PHASE_BAR();
    }
  }

  // ---------------- epilogue ----------------
  if constexpr (MODE == 1) {
    // fused RoPE (Q/K regions) or passthrough (V region)
    if (n0 < 2560) {
      const float scale = (n0 < 2048) ? 0.125f * LOG2E : 1.0f;
      const int d0 = l16, d1 = l16 + 32;
      const int e0 = l16 + 16, e1 = l16 + 48;
#pragma unroll
      for (int mf = 0; mf < 8; mf++) {
#pragma unroll
        for (int r = 0; r < 4; r++) {
          size_t rg = (size_t)(m0 + wm * 128 + mf * 16 + quad * 4 + r);
          int s = (int)(rg & (SEQ - 1));
          const float* cb = fc + s * HDIM;
          const float* sb = fs + s * HDIM;
          float x0 = acc[mf][0][r], x2 = acc[mf][2][r];
          float y1 = acc[mf][1][r], y3 = acc[mf][3][r];
          float o0 = (x0 * cb[d0] - x2 * sb[d0]) * scale;
          float o2 = (x2 * cb[d1] + x0 * sb[d1]) * scale;
          float o1 = (y1 * cb[e0] - y3 * sb[e0]) * scale;
          float o3 = (y3 * cb[e1] + y1 * sb[e1]) * scale;
          ushort* Cr = (ushort*)C + rg * N + n0 + wn * 64 + l16;
          Cr[0]  = f2bf(o0);
          Cr[16] = f2bf(o1);
          Cr[32] = f2bf(o2);
          Cr[48] = f2bf(o3);
        }
      }
      return;
    }
  }
#pragma unroll
  for (int mf = 0; mf < 8; mf++) {
#pragma unroll
    for (int r = 0; r < 4; r++) {
      size_t rg = (size_t)(m0 + wm * 128 + mf * 16 + quad * 4 + r);
#pragma unroll
      for (int nf = 0; nf < NF; nf++) {
        int cg = n0 + wn * (16 * NF) + nf * 16 + l16;
        if constexpr (sizeof(OutT) == 2)
          C[rg * N + cg] = f2bf(acc[mf][nf][r]);
        else
          C[rg * N + cg] = acc[mf][nf][r];
      }
    }
  }
}

// ---------------- MFMA flash attention v7: split-K heavy blocks ----------------
// 24 parts x 64 (b,h) = 1536 blocks (5 resident/CU + backfill):
//   p<16:  qblk = 15-(p>>1), half = p&1 -> K-range [half*(qblk+1), (half+1)*(qblk+1))
//          (split; writes f32 unnormalized o + (m,l) partials, merged later)
//   p>=16: qblk = 23-p, full range [0, 2qblk+2) (unsplit; writes O directly)
// Heavy-first: tiny parts (p 20-23) dispatch last -> true backfill.
// Critical path: 32 -> 16 tiles. Split0 parts are dense (no diagonal).
__global__ __launch_bounds__(256, 4) void attn_mfma(const ushort* __restrict__ QKV,
                                                    ushort* __restrict__ O,
                                                    float* __restrict__ Opart,
                                                    float* __restrict__ ml) {
  __shared__ ushort Ks[64][72];     // [key][d]
  __shared__ ushort Vt[64][72];     // [d][key]
  __shared__ ushort Pw[4][16][72];  // per-wave P[q][key], reused per frag
  const int tid = threadIdx.x;
  const int lane = tid & 63, wave = tid >> 6;
  const int quad = lane >> 4, l16 = lane & 15;

  const int bid = blockIdx.x;
  const int p = bid >> 6;
  const int bh = bid & 63;
  int qblk, t0, t1, half;
  bool split;
  if (p < 16) {
    split = true;
    half = p & 1;
    qblk = 15 - (p >> 1);
    t0 = half * (qblk + 1);
    t1 = t0 + qblk + 1;
  } else {
    split = false;
    half = 0;
    qblk = 23 - p;
    t0 = 0;
    t1 = 2 * qblk + 2;
  }

  const int b = bh >> 5, h = bh & 31, kh = h >> 2;
  const int wrow = qblk * 128 + wave * 32;  // this wave's first q row (global)

  // Q fragments: f=0 rows [wrow, wrow+16), f=1 rows [wrow+16, wrow+32)
  short8 qf[2][2];
#pragma unroll
  for (int f = 0; f < 2; f++)
#pragma unroll
    for (int c = 0; c < 2; c++)
      qf[f][c] = *(const short8*)(QKV +
          (size_t)(b * SEQ + wrow + f * 16 + l16) * QKV_LD +
          h * HDIM + c * 32 + quad * 8);

  f32x4 o[2][4] = {};
  float m[2] = {-INFINITY, -INFINITY}, l[2] = {0.f, 0.f};

  const ushort* Kbase = QKV + (size_t)b * SEQ * QKV_LD + 2048 + kh * HDIM;
  const ushort* Vbase = Kbase + 512;
  const int kp = tid & 31, dg = tid >> 5;

  for (int t = t0; t < t1; t++) {
    const int k0 = t * 64;
    __syncthreads();
    {
      const float4* kpp = (const float4*)(Kbase + (size_t)(k0 + lane) * QKV_LD + wave * 16);
      float4 kv0 = kpp[0], kv1 = kpp[1];
      const uint4* va4 = (const uint4*)(Vbase + (size_t)(k0 + 2 * kp) * QKV_LD + dg * 8);
      const uint4* vb4 = (const uint4*)(Vbase + (size_t)(k0 + 2 * kp + 1) * QKV_LD + dg * 8);
      uint4 va = va4[0], vb = vb4[0];
      *(float4*)&Ks[lane][wave * 16] = kv0;
      *(float4*)&Ks[lane][wave * 16 + 8] = kv1;
      const unsigned* vaw = (const unsigned*)&va;
      const unsigned* vbw = (const unsigned*)&vb;
#pragma unroll
      for (int j = 0; j < 8; j++) {
        unsigned pk = (j & 1)
            ? __builtin_amdgcn_perm(vbw[j >> 1], vaw[j >> 1], 0x07060302)
            : __builtin_amdgcn_perm(vbw[j >> 1], vaw[j >> 1], 0x05040100);
        *(unsigned*)&Vt[dg * 8 + j][2 * kp] = pk;
      }
    }
    __syncthreads();

    // wave fully below diagonal? (both frags fully masked -> only staging needed)
    if (k0 > wrow + 31) continue;
    const bool a0 = (k0 <= wrow + 15);  // frag 0 has any active keys

    // QK^T for both frags, kf shared
    f32x4 s0[4], s1[4];
    __builtin_amdgcn_s_setprio(1);
#pragma unroll
    for (int nt = 0; nt < 4; nt++) {
      short8 kf0 = *(short8*)&Ks[nt * 16 + l16][quad * 8];
      short8 kf1 = *(short8*)&Ks[nt * 16 + l16][32 + quad * 8];
      f32x4 z1 = {};
      z1 = __builtin_amdgcn_mfma_f32_16x16x32_bf16(kf0, qf[1][0], z1, 0, 0, 0);
      s1[nt] = __builtin_amdgcn_mfma_f32_16x16x32_bf16(kf1, qf[1][1], z1, 0, 0, 0);
      if (a0) {
        f32x4 z0 = {};
        z0 = __builtin_amdgcn_mfma_f32_16x16x32_bf16(kf0, qf[0][0], z0, 0, 0, 0);
        s0[nt] = __builtin_amdgcn_mfma_f32_16x16x32_bf16(kf1, qf[0][1], z0, 0, 0, 0);
      }
    }
    __builtin_amdgcn_s_setprio(0);

    // causal masking (diagonal region only)
    if (k0 + 63 > wrow + 16) {  // frag 1 diagonal
      const int lim1 = wrow + 16 + l16 - k0;
#pragma unroll
      for (int nt = 0; nt < 4; nt++)
#pragma unroll
        for (int r = 0; r < 4; r++)
          if (nt * 16 + quad * 4 + r > lim1) s1[nt][r] = -INFINITY;
    }
    if (a0 && k0 + 63 > wrow) {  // frag 0 diagonal
      const int lim0 = wrow + l16 - k0;
#pragma unroll
      for (int nt = 0; nt < 4; nt++)
#pragma unroll
        for (int r = 0; r < 4; r++)
          if (nt * 16 + quad * 4 + r > lim0) s0[nt][r] = -INFINITY;
    }

    // online softmax (T13 defer-max), Pw reused per frag
    auto smx = [&](f32x4 (&s)[4], float& mm, float& ll, f32x4 (&oo)[4]) {
      float mx = s[0][0];
#pragma unroll
      for (int nt = 0; nt < 4; nt++)
#pragma unroll
        for (int r = 0; r < 4; r++) mx = fmaxf(mx, s[nt][r]);
      mx = fmaxf(mx, __shfl_xor(mx, 16));
      mx = fmaxf(mx, __shfl_xor(mx, 32));
      if (!__all(mx <= mm + 8.f)) {
        float mnew = fmaxf(mm, mx);
        float al = hw_exp2(mm - mnew);
        mm = mnew;
        ll *= al;
#pragma unroll
        for (int dt = 0; dt < 4; dt++)
#pragma unroll
          for (int r = 0; r < 4; r++) oo[dt][r] *= al;
      }
      float psum = 0.f;
#pragma unroll
      for (int nt = 0; nt < 4; nt++) {
        float p0 = hw_exp2(s[nt][0] - mm), p1 = hw_exp2(s[nt][1] - mm);
        float p2 = hw_exp2(s[nt][2] - mm), p3 = hw_exp2(s[nt][3] - mm);
        psum += (p0 + p1) + (p2 + p3);
        unsigned lo = __builtin_amdgcn_perm(fbits(p1), fbits(p0), 0x07060302);
        unsigned hi = __builtin_amdgcn_perm(fbits(p3), fbits(p2), 0x07060302);
        uint2 pk; pk.x = lo; pk.y = hi;
        *(uint2*)&Pw[wave][l16][nt * 16 + quad * 4] = pk;
      }
      psum += __shfl_xor(psum, 16);
      psum += __shfl_xor(psum, 32);
      ll += psum;
    };

    short8 pf00, pf01, pf10, pf11;
    if (a0) {
      smx(s0, m[0], l[0], o[0]);
      pf00 = *(short8*)&Pw[wave][l16][quad * 8];
      pf01 = *(short8*)&Pw[wave][l16][32 + quad * 8];
    }
    smx(s1, m[1], l[1], o[1]);
    pf10 = *(short8*)&Pw[wave][l16][quad * 8];
    pf11 = *(short8*)&Pw[wave][l16][32 + quad * 8];

    // PV for both frags, vf shared
    __builtin_amdgcn_s_setprio(1);
#pragma unroll
    for (int dt = 0; dt < 4; dt++) {
      short8 vf0 = *(short8*)&Vt[dt * 16 + l16][quad * 8];
      short8 vf1 = *(short8*)&Vt[dt * 16 + l16][32 + quad * 8];
      o[1][dt] = __builtin_amdgcn_mfma_f32_16x16x32_bf16(vf0, pf10, o[1][dt], 0, 0, 0);
      o[1][dt] = __builtin_amdgcn_mfma_f32_16x16x32_bf16(vf1, pf11, o[1][dt], 0, 0, 0);
      if (a0) {
        o[0][dt] = __builtin_amdgcn_mfma_f32_16x16x32_bf16(vf0, pf00, o[0][dt], 0, 0, 0);
        o[0][dt] = __builtin_amdgcn_mfma_f32_16x16x32_bf16(vf1, pf01, o[0][dt], 0, 0, 0);
      }
    }
    __builtin_amdgcn_s_setprio(0);
  }

  if (split) {
    // partial write: unnormalized o (f32) + (m,l) per row/head
    const int lrb = b * 1024 + (qblk - 8) * 128 + wave * 32;
#pragma unroll
    for (int f = 0; f < 2; f++) {
      const int lr = lrb + f * 16 + l16;
      if (quad == 0) {
        float2* mlp = (float2*)ml + ((size_t)half * 2048 + lr) * 32 + h;
        *mlp = make_float2(m[f], l[f]);
      }
      float* Op = Opart + ((size_t)half * 2048 + lr) * 2048 + h * 64;
#pragma unroll
      for (int dt = 0; dt < 4; dt++)
        *(f32x4*)&Op[dt * 16 + quad * 4] = o[f][dt];
    }
  } else {
#pragma unroll
    for (int f = 0; f < 2; f++) {
      float inv = 1.0f / l[f];
      size_t rowg = (size_t)(b * SEQ + wrow + f * 16 + l16) * EMBED + h * HDIM;
#pragma unroll
      for (int dt = 0; dt < 4; dt++) {
        ushort q0 = f2bf(o[f][dt][0] * inv), q1 = f2bf(o[f][dt][1] * inv);
        ushort q2 = f2bf(o[f][dt][2] * inv), q3 = f2bf(o[f][dt][3] * inv);
        uint2 pk;
        pk.x = (unsigned)q0 | ((unsigned)q1 << 16);
        pk.y = (unsigned)q2 | ((unsigned)q3 << 16);
        *(uint2*)&O[rowg + dt * 16 + quad * 4] = pk;
      }
    }
  }
}

// ---------------- merge the two K-halves for split rows (seq 1024..2047) -------------
__global__ __launch_bounds__(256) void attn_merge(const float* __restrict__ Opart,
                                                  const float* __restrict__ ml,
                                                  ushort* __restrict__ O) {
  int idx = blockIdx.x * 256 + threadIdx.x;  // 524288 threads: 2048 rows x 256 colgrps
  int lr = idx >> 8;
  int cg = (idx & 255) * 8;
  int h = cg >> 6;
  float2 ml0 = ((const float2*)ml)[((size_t)0 * 2048 + lr) * 32 + h];
  float2 ml1 = ((const float2*)ml)[((size_t)1 * 2048 + lr) * 32 + h];
  float M = fmaxf(ml0.x, ml1.x);
  float a0 = hw_exp2(ml0.x - M), a1 = hw_exp2(ml1.x - M);
  float inv = 1.0f / (ml0.y * a0 + ml1.y * a1);
  const float4* p0 = (const float4*)(Opart + ((size_t)0 * 2048 + lr) * 2048 + cg);
  const float4* p1 = (const float4*)(Opart + ((size_t)1 * 2048 + lr) * 2048 + cg);
  float4 x0 = p0[0], x1 = p0[1];
  float4 y0 = p1[0], y1 = p1[1];
  union { uint4 v; ushort u[8]; } pk;
  pk.u[0] = f2bf((x0.x * a0 + y0.x * a1) * inv);
  pk.u[1] = f2bf((x0.y * a0 + y0.y * a1) * inv);
  pk.u[2] = f2bf((x0.z * a0 + y0.z * a1) * inv);
  pk.u[3] = f2bf((x0.w * a0 + y0.w * a1) * inv);
  pk.u[4] = f2bf((x1.x * a0 + y1.x * a1) * inv);
  pk.u[5] = f2bf((x1.y * a0 + y1.y * a1) * inv);
  pk.u[6] = f2bf((x1.z * a0 + y1.z * a1) * inv);
  pk.u[7] = f2bf((x1.w * a0 + y1.w * a1) * inv);
  int b = lr >> 10;
  int r = lr & 1023;
  size_t grow = (size_t)b * SEQ + 1024 + r;
  *(uint4*)&O[grow * EMBED + cg] = pk.v;
}

// ---------------- launch ----------------
extern "C" void kernel_launch(void* const* d_in, const int* in_sizes, int n_in,
                              void* d_out, int out_size, void* d_ws, size_t ws_size,
                              hipStream_t stream) {
  const float* x = (const float*)d_in[0];
  const float* fcos = (const float*)d_in[1];
  const float* fsin = (const float*)d_in[2];
  const float* wq = (const float*)d_in[3];
  const float* wk = (const float*)d_in[4];
  const float* wv = (const float*)d_in[5];
  const float* wo = (const float*)d_in[6];
  float* out = (float*)d_out;

  const int M = BATCH * SEQ;  // 4096
  ushort* ws = (ushort*)d_ws;
  ushort* xb = ws;
  ushort* wqkv = xb + (size_t)M * EMBED;
  ushort* wob = wqkv + (size_t)QKV_LD * EMBED;
  ushort* QKVb = wob + (size_t)EMBED * EMBED;
  ushort* Ab = QKVb + (size_t)M * QKV_LD;
  float* Opart = (float*)(Ab + (size_t)M * EMBED);      // 2 x 2048 x 2048 f32 = 32MB
  float* mlbuf = Opart + (size_t)2 * 2048 * 2048;       // 2 x 2048 x 32 float2 = 1MB

  dim3 blk(256);
  cvt_all<<<9216, blk, 0, stream>>>(x, wq, wk, wv, wo, xb, wqkv, wob);

  // QKV projection + fused RoPE: 256x256 8-phase GEMM (192 blocks)
  gemm8p<256, 1, ushort><<<dim3(QKV_LD / 256, M / 256), dim3(512), 0, stream>>>(
      xb, wqkv, QKVb, fcos, fsin, M, QKV_LD, EMBED);

  attn_mfma<<<dim3(1536), blk, 0, stream>>>(QKVb, Ab, Opart, mlbuf);
  attn_merge<<<dim3(2048), blk, 0, stream>>>(Opart, mlbuf, Ab);

  // output projection: 256x128 8-phase GEMM (256 blocks = 1/CU)
  gemm8p<128, 0, float><<<dim3(EMBED / 128, M / 256), dim3(512), 0, stream>>>(
      Ab, wob, out, nullptr, nullptr, M, EMBED, EMBED);
}

// Round 11
// 307.425 us; speedup vs baseline: 1.0630x; 1.0630x over previous
//
#include <hip/hip_runtime.h>

#define BATCH 2
#define SEQ 2048
#define EMBED 2048
#define NHEADS 32
#define NKV 8
#define HDIM 64
#define QKV_LD 3072  // fused [Q(2048) | K(512) | V(512)] row stride
#define LOG2E 1.44269504088896f

typedef __attribute__((ext_vector_type(8))) short short8;
typedef __attribute__((ext_vector_type(4))) float f32x4;

__device__ inline float hw_exp2(float x) { return __builtin_amdgcn_exp2f(x); }

__device__ inline ushort f2bf(float f) {
  union { float f; unsigned u; } v{f};
  unsigned r = v.u + 0x7FFF + ((v.u >> 16) & 1);
  return (ushort)(r >> 16);
}
__device__ inline float bf2f(ushort u) {
  union { unsigned u; float f; } v{((unsigned)u) << 16};
  return v.f;
}
__device__ inline unsigned fbits(float f) {
  union { float f; unsigned u; } v{f};
  return v.u;
}

__device__ inline void gload16(const ushort* g, ushort* l) {
  __builtin_amdgcn_global_load_lds(
      (const __attribute__((address_space(1))) unsigned*)g,
      (__attribute__((address_space(3))) unsigned*)l, 16, 0, 0);
}

#define PHASE_BAR()                          \
  do {                                       \
    __builtin_amdgcn_sched_barrier(0);       \
    __builtin_amdgcn_s_barrier();            \
    __builtin_amdgcn_sched_barrier(0);       \
  } while (0)

// ---------------- fused fp32 -> bf16 convert (all 5 tensors, 1 launch) ----------------
__global__ __launch_bounds__(256) void cvt_all(const float* __restrict__ x,
                                               const float* __restrict__ wq,
                                               const float* __restrict__ wk,
                                               const float* __restrict__ wv,
                                               const float* __restrict__ wo,
                                               ushort* __restrict__ xb,
                                               ushort* __restrict__ wqkv,
                                               ushort* __restrict__ wob) {
  size_t e = (size_t)(blockIdx.x * blockDim.x + threadIdx.x) * 8;
  const float* src;
  ushort* dst;
  if (e < 8388608u) { src = x + e; dst = xb + e; }
  else if (e < 12582912u) { size_t o = e - 8388608u; src = wq + o; dst = wqkv + o; }
  else if (e < 13631488u) { size_t o = e - 12582912u; src = wk + o; dst = wqkv + 4194304u + o; }
  else if (e < 14680064u) { size_t o = e - 13631488u; src = wv + o; dst = wqkv + 5242880u + o; }
  else { size_t o = e - 14680064u; src = wo + o; dst = wob + o; }
  float4 v0 = ((const float4*)src)[0];
  float4 v1 = ((const float4*)src)[1];
  union { uint4 v; ushort u[8]; } pk;
  pk.u[0] = f2bf(v0.x); pk.u[1] = f2bf(v0.y); pk.u[2] = f2bf(v0.z); pk.u[3] = f2bf(v0.w);
  pk.u[4] = f2bf(v1.x); pk.u[5] = f2bf(v1.y); pk.u[6] = f2bf(v1.z); pk.u[7] = f2bf(v1.w);
  *(uint4*)dst = pk.v;
}

// ---------------- 8-phase bf16 GEMM template: C[M,N] = A * B^T (v10, frozen) --------
template <int BN, int MODE, typename OutT>
__global__ __launch_bounds__(512) void gemm8p(const ushort* __restrict__ Ag,
                                              const ushort* __restrict__ Bg,
                                              OutT* __restrict__ C,
                                              const float* __restrict__ fc,
                                              const float* __restrict__ fs,
                                              int M, int N, int K) {
  constexpr int NF = BN / 64;  // per-wave 16-col fragments
  __shared__ ushort As[2][2][256][32];
  __shared__ ushort Bs[2][2][BN][32];
  const int tid = threadIdx.x;
  const int lane = tid & 63, wave = tid >> 6;
  const int quad = lane >> 4, l16 = lane & 15;
  const int wm = wave >> 2, wn = wave & 3;  // 2M x 4N
  const int m0 = blockIdx.y * 256, n0 = blockIdx.x * BN;
  const int NT = K >> 6;

  auto stA = [&](int Tn, int h) {
    const int r0 = h * 128 + wave * 16;
    const ushort* g = Ag + (size_t)(m0 + r0 + (lane >> 2)) * K + Tn * 64 + (lane & 3) * 8;
    gload16(g, &As[Tn & 1][0][r0][0]);
    gload16(g + 32, &As[Tn & 1][1][r0][0]);
  };
  auto stB = [&](int Tn, int h) {
    const int r0 = h * 128 + wave * 16;
    const ushort* g = Bg + (size_t)(n0 + r0 + (lane >> 2)) * K + Tn * 64 + (lane & 3) * 8;
    gload16(g, &Bs[Tn & 1][0][r0][0]);
    gload16(g + 32, &Bs[Tn & 1][1][r0][0]);
  };

  f32x4 acc[8][NF] = {};

  // prologue: stage K-tile 0 fully
  stA(0, 0); stA(0, 1);
  stB(0, 0);
  if constexpr (BN == 256) stB(0, 1);

  for (int T = 0; T < NT; ++T) {
    const int bf = T & 1;
    asm volatile("s_waitcnt vmcnt(0)" ::: "memory");
    PHASE_BAR();

    // B-frags for the whole K-tile (phase 0 reads)
    short8 bfr[NF][2];
#pragma unroll
    for (int nf = 0; nf < NF; nf++)
#pragma unroll
      for (int kk = 0; kk < 2; kk++)
        bfr[nf][kk] = *(short8*)&Bs[bf][kk][wn * (16 * NF) + nf * 16 + l16][quad * 8];

#pragma unroll
    for (int q = 0; q < 4; q++) {
      short8 afr[2][2];
#pragma unroll
      for (int mq = 0; mq < 2; mq++)
#pragma unroll
        for (int kk = 0; kk < 2; kk++)
          afr[mq][kk] = *(short8*)&As[bf][kk][wm * 128 + (2 * q + mq) * 16 + l16][quad * 8];

      // per-phase staging of tile T+1 into the other buffer (v8 schedule)
      if (T + 1 < NT) {
        if (q == 0) stA(T + 1, 0);
        else if (q == 1) stA(T + 1, 1);
        else if (q == 2) stB(T + 1, 0);
        else if constexpr (BN == 256) stB(T + 1, 1);
      }

      __builtin_amdgcn_s_setprio(1);
#pragma unroll
      for (int mq = 0; mq < 2; mq++)
#pragma unroll
        for (int nf = 0; nf < NF; nf++)
#pragma unroll
          for (int kk = 0; kk < 2; kk++)
            acc[2 * q + mq][nf] = __builtin_amdgcn_mfma_f32_16x16x32_bf16(
                afr[mq][kk], bfr[nf][kk], acc[2 * q + mq][nf], 0, 0, 0);
      __builtin_amdgcn_s_setprio(0);
      PHASE_BAR();
    }
  }

  // ---------------- epilogue ----------------
  if constexpr (MODE == 1) {
    // fused RoPE (Q/K regions) or passthrough (V region)
    if (n0 < 2560) {
      const float scale = (n0 < 2048) ? 0.125f * LOG2E : 1.0f;
      const int d0 = l16, d1 = l16 + 32;
      const int e0 = l16 + 16, e1 = l16 + 48;
#pragma unroll
      for (int mf = 0; mf < 8; mf++) {
#pragma unroll
        for (int r = 0; r < 4; r++) {
          size_t rg = (size_t)(m0 + wm * 128 + mf * 16 + quad * 4 + r);
          int s = (int)(rg & (SEQ - 1));
          const float* cb = fc + s * HDIM;
          const float* sb = fs + s * HDIM;
          float x0 = acc[mf][0][r], x2 = acc[mf][2][r];
          float y1 = acc[mf][1][r], y3 = acc[mf][3][r];
          float o0 = (x0 * cb[d0] - x2 * sb[d0]) * scale;
          float o2 = (x2 * cb[d1] + x0 * sb[d1]) * scale;
          float o1 = (y1 * cb[e0] - y3 * sb[e0]) * scale;
          float o3 = (y3 * cb[e1] + y1 * sb[e1]) * scale;
          ushort* Cr = (ushort*)C + rg * N + n0 + wn * 64 + l16;
          Cr[0]  = f2bf(o0);
          Cr[16] = f2bf(o1);
          Cr[32] = f2bf(o2);
          Cr[48] = f2bf(o3);
        }
      }
      return;
    }
  }
#pragma unroll
  for (int mf = 0; mf < 8; mf++) {
#pragma unroll
    for (int r = 0; r < 4; r++) {
      size_t rg = (size_t)(m0 + wm * 128 + mf * 16 + quad * 4 + r);
#pragma unroll
      for (int nf = 0; nf < NF; nf++) {
        int cg = n0 + wn * (16 * NF) + nf * 16 + l16;
        if constexpr (sizeof(OutT) == 2)
          C[rg * N + cg] = f2bf(acc[mf][nf][r]);
        else
          C[rg * N + cg] = acc[mf][nf][r];
      }
    }
  }
}

// ---------------- MFMA flash attention v8 ----------------
// v6 structure (single kernel, CU-balanced 1024-block mapping) +
// serial-chain reduction in the softmax:
//  - per-lane PARTIAL l (sum): quad-reduction deferred to the epilogue
//    (removes 2 __shfl_xor ~120cy DS-latency ops per frag per tile).
//  - ballot-gated max shuffles: __all(partial_max <= m+8) over lanes is
//    EXACTLY equivalent to the old __all(rowmax <= m+8) ("no row grew"),
//    so the 2 max shuffles + rescale run only when a row actually grows
//    (rare under T13). Common path per tile: ZERO cross-lane ops.
__global__ __launch_bounds__(256, 4) void attn_mfma(const ushort* __restrict__ QKV,
                                                    ushort* __restrict__ O) {
  __shared__ ushort Ks[64][72];     // [key][d]
  __shared__ ushort Vt[64][72];     // [d][key]
  __shared__ ushort Pw[4][16][72];  // per-wave P[q][key], reused per frag
  const int tid = threadIdx.x;
  const int lane = tid & 63, wave = tid >> 6;
  const int quad = lane >> 4, l16 = lane & 15;

  // CU-balanced (qblk, bh) derivation (v6)
  const int bid = blockIdx.x;
  const int qq = bid >> 8;         // quarter 0..3
  const int j4 = (bid >> 6) & 3;   // 0..3
  const int bh = bid & 63;
  const int qblk = (qq >> 1) * 8 + ((qq & 1) ? 7 - j4 : j4);

  const int b = bh >> 5, h = bh & 31, kh = h >> 2;
  const int ntiles = 2 * qblk + 2;          // causal K-range of this 128-row block
  const int wrow = qblk * 128 + wave * 32;  // this wave's first q row (global)

  // Q fragments: f=0 rows [wrow, wrow+16), f=1 rows [wrow+16, wrow+32)
  short8 qf[2][2];
#pragma unroll
  for (int f = 0; f < 2; f++)
#pragma unroll
    for (int c = 0; c < 2; c++)
      qf[f][c] = *(const short8*)(QKV +
          (size_t)(b * SEQ + wrow + f * 16 + l16) * QKV_LD +
          h * HDIM + c * 32 + quad * 8);

  f32x4 o[2][4] = {};
  float m[2] = {-INFINITY, -INFINITY}, l[2] = {0.f, 0.f};  // l is per-LANE partial

  const ushort* Kbase = QKV + (size_t)b * SEQ * QKV_LD + 2048 + kh * HDIM;
  const ushort* Vbase = Kbase + 512;
  const int kp = tid & 31, dg = tid >> 5;

  for (int t = 0; t < ntiles; t++) {
    const int k0 = t * 64;
    __syncthreads();
    {
      const float4* kpp = (const float4*)(Kbase + (size_t)(k0 + lane) * QKV_LD + wave * 16);
      float4 kv0 = kpp[0], kv1 = kpp[1];
      const uint4* va4 = (const uint4*)(Vbase + (size_t)(k0 + 2 * kp) * QKV_LD + dg * 8);
      const uint4* vb4 = (const uint4*)(Vbase + (size_t)(k0 + 2 * kp + 1) * QKV_LD + dg * 8);
      uint4 va = va4[0], vb = vb4[0];
      *(float4*)&Ks[lane][wave * 16] = kv0;
      *(float4*)&Ks[lane][wave * 16 + 8] = kv1;
      const unsigned* vaw = (const unsigned*)&va;
      const unsigned* vbw = (const unsigned*)&vb;
#pragma unroll
      for (int j = 0; j < 8; j++) {
        unsigned pk = (j & 1)
            ? __builtin_amdgcn_perm(vbw[j >> 1], vaw[j >> 1], 0x07060302)
            : __builtin_amdgcn_perm(vbw[j >> 1], vaw[j >> 1], 0x05040100);
        *(unsigned*)&Vt[dg * 8 + j][2 * kp] = pk;
      }
    }
    __syncthreads();

    // wave fully below diagonal? (both frags fully masked -> only staging needed)
    if (k0 > wrow + 31) continue;
    const bool a0 = (k0 <= wrow + 15);  // frag 0 has any active keys

    // QK^T for both frags, kf shared
    f32x4 s0[4], s1[4];
    __builtin_amdgcn_s_setprio(1);
#pragma unroll
    for (int nt = 0; nt < 4; nt++) {
      short8 kf0 = *(short8*)&Ks[nt * 16 + l16][quad * 8];
      short8 kf1 = *(short8*)&Ks[nt * 16 + l16][32 + quad * 8];
      f32x4 z1 = {};
      z1 = __builtin_amdgcn_mfma_f32_16x16x32_bf16(kf0, qf[1][0], z1, 0, 0, 0);
      s1[nt] = __builtin_amdgcn_mfma_f32_16x16x32_bf16(kf1, qf[1][1], z1, 0, 0, 0);
      if (a0) {
        f32x4 z0 = {};
        z0 = __builtin_amdgcn_mfma_f32_16x16x32_bf16(kf0, qf[0][0], z0, 0, 0, 0);
        s0[nt] = __builtin_amdgcn_mfma_f32_16x16x32_bf16(kf1, qf[0][1], z0, 0, 0, 0);
      }
    }
    __builtin_amdgcn_s_setprio(0);

    // causal masking (diagonal region only)
    if (k0 + 63 > wrow + 16) {  // frag 1 diagonal
      const int lim1 = wrow + 16 + l16 - k0;
#pragma unroll
      for (int nt = 0; nt < 4; nt++)
#pragma unroll
        for (int r = 0; r < 4; r++)
          if (nt * 16 + quad * 4 + r > lim1) s1[nt][r] = -INFINITY;
    }
    if (a0 && k0 + 63 > wrow) {  // frag 0 diagonal
      const int lim0 = wrow + l16 - k0;
#pragma unroll
      for (int nt = 0; nt < 4; nt++)
#pragma unroll
        for (int r = 0; r < 4; r++)
          if (nt * 16 + quad * 4 + r > lim0) s0[nt][r] = -INFINITY;
    }

    // online softmax: T13 defer-max + ballot-gated shuffles + per-lane partial l
    auto smx = [&](f32x4 (&s)[4], float& mm, float& ll, f32x4 (&oo)[4]) {
      float mx = s[0][0];
#pragma unroll
      for (int nt = 0; nt < 4; nt++)
#pragma unroll
        for (int r = 0; r < 4; r++) mx = fmaxf(mx, s[nt][r]);
      // __all over lane-partials == __all over row-maxima: shuffle-free gate
      if (!__all(mx <= mm + 8.f)) {
        mx = fmaxf(mx, __shfl_xor(mx, 16));
        mx = fmaxf(mx, __shfl_xor(mx, 32));
        float mnew = fmaxf(mm, mx);
        float al = hw_exp2(mm - mnew);  // row-uniform -> valid for per-lane ll
        mm = mnew;
        ll *= al;
#pragma unroll
        for (int dt = 0; dt < 4; dt++)
#pragma unroll
          for (int r = 0; r < 4; r++) oo[dt][r] *= al;
      }
      float psum = 0.f;
#pragma unroll
      for (int nt = 0; nt < 4; nt++) {
        float p0 = hw_exp2(s[nt][0] - mm), p1 = hw_exp2(s[nt][1] - mm);
        float p2 = hw_exp2(s[nt][2] - mm), p3 = hw_exp2(s[nt][3] - mm);
        psum += (p0 + p1) + (p2 + p3);
        unsigned lo = __builtin_amdgcn_perm(fbits(p1), fbits(p0), 0x07060302);
        unsigned hi = __builtin_amdgcn_perm(fbits(p3), fbits(p2), 0x07060302);
        uint2 pk; pk.x = lo; pk.y = hi;
        *(uint2*)&Pw[wave][l16][nt * 16 + quad * 4] = pk;
      }
      ll += psum;  // per-lane partial; quad-reduced in epilogue
    };

    short8 pf00, pf01, pf10, pf11;
    if (a0) {
      smx(s0, m[0], l[0], o[0]);
      pf00 = *(short8*)&Pw[wave][l16][quad * 8];
      pf01 = *(short8*)&Pw[wave][l16][32 + quad * 8];
    }
    smx(s1, m[1], l[1], o[1]);
    pf10 = *(short8*)&Pw[wave][l16][quad * 8];
    pf11 = *(short8*)&Pw[wave][l16][32 + quad * 8];

    // PV for both frags, vf shared
    __builtin_amdgcn_s_setprio(1);
#pragma unroll
    for (int dt = 0; dt < 4; dt++) {
      short8 vf0 = *(short8*)&Vt[dt * 16 + l16][quad * 8];
      short8 vf1 = *(short8*)&Vt[dt * 16 + l16][32 + quad * 8];
      o[1][dt] = __builtin_amdgcn_mfma_f32_16x16x32_bf16(vf0, pf10, o[1][dt], 0, 0, 0);
      o[1][dt] = __builtin_amdgcn_mfma_f32_16x16x32_bf16(vf1, pf11, o[1][dt], 0, 0, 0);
      if (a0) {
        o[0][dt] = __builtin_amdgcn_mfma_f32_16x16x32_bf16(vf0, pf00, o[0][dt], 0, 0, 0);
        o[0][dt] = __builtin_amdgcn_mfma_f32_16x16x32_bf16(vf1, pf01, o[0][dt], 0, 0, 0);
      }
    }
    __builtin_amdgcn_s_setprio(0);
  }

#pragma unroll
  for (int f = 0; f < 2; f++) {
    // quad-reduce the per-lane partial l (once per frag)
    float lr = l[f];
    lr += __shfl_xor(lr, 16);
    lr += __shfl_xor(lr, 32);
    float inv = 1.0f / lr;
    size_t rowg = (size_t)(b * SEQ + wrow + f * 16 + l16) * EMBED + h * HDIM;
#pragma unroll
    for (int dt = 0; dt < 4; dt++) {
      ushort q0 = f2bf(o[f][dt][0] * inv), q1 = f2bf(o[f][dt][1] * inv);
      ushort q2 = f2bf(o[f][dt][2] * inv), q3 = f2bf(o[f][dt][3] * inv);
      uint2 pk;
      pk.x = (unsigned)q0 | ((unsigned)q1 << 16);
      pk.y = (unsigned)q2 | ((unsigned)q3 << 16);
      *(uint2*)&O[rowg + dt * 16 + quad * 4] = pk;
    }
  }
}

// ---------------- launch ----------------
extern "C" void kernel_launch(void* const* d_in, const int* in_sizes, int n_in,
                              void* d_out, int out_size, void* d_ws, size_t ws_size,
                              hipStream_t stream) {
  const float* x = (const float*)d_in[0];
  const float* fcos = (const float*)d_in[1];
  const float* fsin = (const float*)d_in[2];
  const float* wq = (const float*)d_in[3];
  const float* wk = (const float*)d_in[4];
  const float* wv = (const float*)d_in[5];
  const float* wo = (const float*)d_in[6];
  float* out = (float*)d_out;

  const int M = BATCH * SEQ;  // 4096
  ushort* ws = (ushort*)d_ws;
  ushort* xb = ws;
  ushort* wqkv = xb + (size_t)M * EMBED;
  ushort* wob = wqkv + (size_t)QKV_LD * EMBED;
  ushort* QKVb = wob + (size_t)EMBED * EMBED;
  ushort* Ab = QKVb + (size_t)M * QKV_LD;

  dim3 blk(256);
  cvt_all<<<9216, blk, 0, stream>>>(x, wq, wk, wv, wo, xb, wqkv, wob);

  // QKV projection + fused RoPE: 256x256 8-phase GEMM (192 blocks)
  gemm8p<256, 1, ushort><<<dim3(QKV_LD / 256, M / 256), dim3(512), 0, stream>>>(
      xb, wqkv, QKVb, fcos, fsin, M, QKV_LD, EMBED);

  attn_mfma<<<dim3(1024), blk, 0, stream>>>(QKVb, Ab);

  // output projection: 256x128 8-phase GEMM (256 blocks = 1/CU)
  gemm8p<128, 0, float><<<dim3(EMBED / 128, M / 256), dim3(512), 0, stream>>>(
      Ab, wob, out, nullptr, nullptr, M, EMBED, EMBED);
}

// Round 12
// 304.790 us; speedup vs baseline: 1.0722x; 1.0086x over previous
//
#include <hip/hip_runtime.h>

#define BATCH 2
#define SEQ 2048
#define EMBED 2048
#define NHEADS 32
#define NKV 8
#define HDIM 64
#define QKV_LD 3072  // fused [Q(2048) | K(512) | V(512)] row stride
#define LOG2E 1.44269504088896f

typedef __attribute__((ext_vector_type(8))) short short8;
typedef __attribute__((ext_vector_type(4))) float f32x4;

__device__ inline float hw_exp2(float x) { return __builtin_amdgcn_exp2f(x); }

__device__ inline ushort f2bf(float f) {
  union { float f; unsigned u; } v{f};
  unsigned r = v.u + 0x7FFF + ((v.u >> 16) & 1);
  return (ushort)(r >> 16);
}
__device__ inline float bf2f(ushort u) {
  union { unsigned u; float f; } v{((unsigned)u) << 16};
  return v.f;
}
__device__ inline unsigned fbits(float f) {
  union { float f; unsigned u; } v{f};
  return v.u;
}

__device__ inline void gload16(const ushort* g, ushort* l) {
  __builtin_amdgcn_global_load_lds(
      (const __attribute__((address_space(1))) unsigned*)g,
      (__attribute__((address_space(3))) unsigned*)l, 16, 0, 0);
}

#define PHASE_BAR()                          \
  do {                                       \
    __builtin_amdgcn_sched_barrier(0);       \
    __builtin_amdgcn_s_barrier();            \
    __builtin_amdgcn_sched_barrier(0);       \
  } while (0)

// ---------------- fused fp32 -> bf16 convert (all 5 tensors, 1 launch) ----------------
__global__ __launch_bounds__(256) void cvt_all(const float* __restrict__ x,
                                               const float* __restrict__ wq,
                                               const float* __restrict__ wk,
                                               const float* __restrict__ wv,
                                               const float* __restrict__ wo,
                                               ushort* __restrict__ xb,
                                               ushort* __restrict__ wqkv,
                                               ushort* __restrict__ wob) {
  size_t e = (size_t)(blockIdx.x * blockDim.x + threadIdx.x) * 8;
  const float* src;
  ushort* dst;
  if (e < 8388608u) { src = x + e; dst = xb + e; }
  else if (e < 12582912u) { size_t o = e - 8388608u; src = wq + o; dst = wqkv + o; }
  else if (e < 13631488u) { size_t o = e - 12582912u; src = wk + o; dst = wqkv + 4194304u + o; }
  else if (e < 14680064u) { size_t o = e - 13631488u; src = wv + o; dst = wqkv + 5242880u + o; }
  else { size_t o = e - 14680064u; src = wo + o; dst = wob + o; }
  float4 v0 = ((const float4*)src)[0];
  float4 v1 = ((const float4*)src)[1];
  union { uint4 v; ushort u[8]; } pk;
  pk.u[0] = f2bf(v0.x); pk.u[1] = f2bf(v0.y); pk.u[2] = f2bf(v0.z); pk.u[3] = f2bf(v0.w);
  pk.u[4] = f2bf(v1.x); pk.u[5] = f2bf(v1.y); pk.u[6] = f2bf(v1.z); pk.u[7] = f2bf(v1.w);
  *(uint4*)dst = pk.v;
}

// ---------------- 8-phase bf16 GEMM template: C[M,N] = A * B^T -----------------------
// v13: T2 bank-conflict swizzle on the [256][32] kk-subtiles.
//   Linear layout frag reads (&As[kk][row][quad*8], 64B rows) have bank bits
//   {row[0], quad, j}: 16 lanes -> 2 groups = 8-WAY conflict (2.94x, G4).
//   Swizzle chunk' = chunk ^ ((row>>1)&3): bank group (row[0], quad^row[2:1])
//   takes 8 distinct values over 16 lanes -> 2 lanes/bank = FREE (m136).
//   Rule #21: LDS dest stays LINEAR (gload16-safe); global SOURCE k-offset is
//   pre-swizzled per-lane; ds_read applies the same XOR (involution).
template <int BN, int MODE, typename OutT>
__global__ __launch_bounds__(512) void gemm8p(const ushort* __restrict__ Ag,
                                              const ushort* __restrict__ Bg,
                                              OutT* __restrict__ C,
                                              const float* __restrict__ fc,
                                              const float* __restrict__ fs,
                                              int M, int N, int K) {
  constexpr int NF = BN / 64;  // per-wave 16-col fragments
  __shared__ ushort As[2][2][256][32];
  __shared__ ushort Bs[2][2][BN][32];
  const int tid = threadIdx.x;
  const int lane = tid & 63, wave = tid >> 6;
  const int quad = lane >> 4, l16 = lane & 15;
  const int wm = wave >> 2, wn = wave & 3;  // 2M x 4N
  const int m0 = blockIdx.y * 256, n0 = blockIdx.x * BN;
  const int NT = K >> 6;

  // stage: lane's 16B lands at LDS row lrow = r0+(lane>>2), chunk lane&3.
  // That physical slot must hold logical chunk (lane&3)^((lrow>>1)&3).
  auto stA = [&](int Tn, int h) {
    const int r0 = h * 128 + wave * 16;
    const int lrow = r0 + (lane >> 2);
    const int sw = ((lane & 3) ^ ((lrow >> 1) & 3)) * 8;
    const ushort* g = Ag + (size_t)(m0 + lrow) * K + Tn * 64 + sw;
    gload16(g, &As[Tn & 1][0][r0][0]);
    gload16(g + 32, &As[Tn & 1][1][r0][0]);
  };
  auto stB = [&](int Tn, int h) {
    const int r0 = h * 128 + wave * 16;
    const int lrow = r0 + (lane >> 2);
    const int sw = ((lane & 3) ^ ((lrow >> 1) & 3)) * 8;
    const ushort* g = Bg + (size_t)(n0 + lrow) * K + Tn * 64 + sw;
    gload16(g, &Bs[Tn & 1][0][r0][0]);
    gload16(g + 32, &Bs[Tn & 1][1][r0][0]);
  };

  f32x4 acc[8][NF] = {};

  // prologue: stage K-tile 0 fully
  stA(0, 0); stA(0, 1);
  stB(0, 0);
  if constexpr (BN == 256) stB(0, 1);

  for (int T = 0; T < NT; ++T) {
    const int bf = T & 1;
    asm volatile("s_waitcnt vmcnt(0)" ::: "memory");
    PHASE_BAR();

    // B-frags for the whole K-tile (phase 0 reads, swizzled chunk)
    short8 bfr[NF][2];
#pragma unroll
    for (int nf = 0; nf < NF; nf++) {
      const int row = wn * (16 * NF) + nf * 16 + l16;
      const int ch = (quad ^ ((row >> 1) & 3)) * 8;
#pragma unroll
      for (int kk = 0; kk < 2; kk++)
        bfr[nf][kk] = *(short8*)&Bs[bf][kk][row][ch];
    }

#pragma unroll
    for (int q = 0; q < 4; q++) {
      short8 afr[2][2];
#pragma unroll
      for (int mq = 0; mq < 2; mq++) {
        const int row = wm * 128 + (2 * q + mq) * 16 + l16;
        const int ch = (quad ^ ((row >> 1) & 3)) * 8;
#pragma unroll
        for (int kk = 0; kk < 2; kk++)
          afr[mq][kk] = *(short8*)&As[bf][kk][row][ch];
      }

      // per-phase staging of tile T+1 into the other buffer (v8 schedule)
      if (T + 1 < NT) {
        if (q == 0) stA(T + 1, 0);
        else if (q == 1) stA(T + 1, 1);
        else if (q == 2) stB(T + 1, 0);
        else if constexpr (BN == 256) stB(T + 1, 1);
      }

      __builtin_amdgcn_s_setprio(1);
#pragma unroll
      for (int mq = 0; mq < 2; mq++)
#pragma unroll
        for (int nf = 0; nf < NF; nf++)
#pragma unroll
          for (int kk = 0; kk < 2; kk++)
            acc[2 * q + mq][nf] = __builtin_amdgcn_mfma_f32_16x16x32_bf16(
                afr[mq][kk], bfr[nf][kk], acc[2 * q + mq][nf], 0, 0, 0);
      __builtin_amdgcn_s_setprio(0);
      PHASE_BAR();
    }
  }

  // ---------------- epilogue ----------------
  if constexpr (MODE == 1) {
    // fused RoPE (Q/K regions) or passthrough (V region)
    if (n0 < 2560) {
      const float scale = (n0 < 2048) ? 0.125f * LOG2E : 1.0f;
      const int d0 = l16, d1 = l16 + 32;
      const int e0 = l16 + 16, e1 = l16 + 48;
#pragma unroll
      for (int mf = 0; mf < 8; mf++) {
#pragma unroll
        for (int r = 0; r < 4; r++) {
          size_t rg = (size_t)(m0 + wm * 128 + mf * 16 + quad * 4 + r);
          int s = (int)(rg & (SEQ - 1));
          const float* cb = fc + s * HDIM;
          const float* sb = fs + s * HDIM;
          float x0 = acc[mf][0][r], x2 = acc[mf][2][r];
          float y1 = acc[mf][1][r], y3 = acc[mf][3][r];
          float o0 = (x0 * cb[d0] - x2 * sb[d0]) * scale;
          float o2 = (x2 * cb[d1] + x0 * sb[d1]) * scale;
          float o1 = (y1 * cb[e0] - y3 * sb[e0]) * scale;
          float o3 = (y3 * cb[e1] + y1 * sb[e1]) * scale;
          ushort* Cr = (ushort*)C + rg * N + n0 + wn * 64 + l16;
          Cr[0]  = f2bf(o0);
          Cr[16] = f2bf(o1);
          Cr[32] = f2bf(o2);
          Cr[48] = f2bf(o3);
        }
      }
      return;
    }
  }
#pragma unroll
  for (int mf = 0; mf < 8; mf++) {
#pragma unroll
    for (int r = 0; r < 4; r++) {
      size_t rg = (size_t)(m0 + wm * 128 + mf * 16 + quad * 4 + r);
#pragma unroll
      for (int nf = 0; nf < NF; nf++) {
        int cg = n0 + wn * (16 * NF) + nf * 16 + l16;
        if constexpr (sizeof(OutT) == 2)
          C[rg * N + cg] = f2bf(acc[mf][nf][r]);
        else
          C[rg * N + cg] = acc[mf][nf][r];
      }
    }
  }
}

// ---------------- MFMA flash attention v8 (v12, frozen) ----------------
__global__ __launch_bounds__(256, 4) void attn_mfma(const ushort* __restrict__ QKV,
                                                    ushort* __restrict__ O) {
  __shared__ ushort Ks[64][72];     // [key][d]
  __shared__ ushort Vt[64][72];     // [d][key]
  __shared__ ushort Pw[4][16][72];  // per-wave P[q][key], reused per frag
  const int tid = threadIdx.x;
  const int lane = tid & 63, wave = tid >> 6;
  const int quad = lane >> 4, l16 = lane & 15;

  // CU-balanced (qblk, bh) derivation (v6)
  const int bid = blockIdx.x;
  const int qq = bid >> 8;         // quarter 0..3
  const int j4 = (bid >> 6) & 3;   // 0..3
  const int bh = bid & 63;
  const int qblk = (qq >> 1) * 8 + ((qq & 1) ? 7 - j4 : j4);

  const int b = bh >> 5, h = bh & 31, kh = h >> 2;
  const int ntiles = 2 * qblk + 2;          // causal K-range of this 128-row block
  const int wrow = qblk * 128 + wave * 32;  // this wave's first q row (global)

  // Q fragments: f=0 rows [wrow, wrow+16), f=1 rows [wrow+16, wrow+32)
  short8 qf[2][2];
#pragma unroll
  for (int f = 0; f < 2; f++)
#pragma unroll
    for (int c = 0; c < 2; c++)
      qf[f][c] = *(const short8*)(QKV +
          (size_t)(b * SEQ + wrow + f * 16 + l16) * QKV_LD +
          h * HDIM + c * 32 + quad * 8);

  f32x4 o[2][4] = {};
  float m[2] = {-INFINITY, -INFINITY}, l[2] = {0.f, 0.f};  // l is per-LANE partial

  const ushort* Kbase = QKV + (size_t)b * SEQ * QKV_LD + 2048 + kh * HDIM;
  const ushort* Vbase = Kbase + 512;
  const int kp = tid & 31, dg = tid >> 5;

  for (int t = 0; t < ntiles; t++) {
    const int k0 = t * 64;
    __syncthreads();
    {
      const float4* kpp = (const float4*)(Kbase + (size_t)(k0 + lane) * QKV_LD + wave * 16);
      float4 kv0 = kpp[0], kv1 = kpp[1];
      const uint4* va4 = (const uint4*)(Vbase + (size_t)(k0 + 2 * kp) * QKV_LD + dg * 8);
      const uint4* vb4 = (const uint4*)(Vbase + (size_t)(k0 + 2 * kp + 1) * QKV_LD + dg * 8);
      uint4 va = va4[0], vb = vb4[0];
      *(float4*)&Ks[lane][wave * 16] = kv0;
      *(float4*)&Ks[lane][wave * 16 + 8] = kv1;
      const unsigned* vaw = (const unsigned*)&va;
      const unsigned* vbw = (const unsigned*)&vb;
#pragma unroll
      for (int j = 0; j < 8; j++) {
        unsigned pk = (j & 1)
            ? __builtin_amdgcn_perm(vbw[j >> 1], vaw[j >> 1], 0x07060302)
            : __builtin_amdgcn_perm(vbw[j >> 1], vaw[j >> 1], 0x05040100);
        *(unsigned*)&Vt[dg * 8 + j][2 * kp] = pk;
      }
    }
    __syncthreads();

    // wave fully below diagonal? (both frags fully masked -> only staging needed)
    if (k0 > wrow + 31) continue;
    const bool a0 = (k0 <= wrow + 15);  // frag 0 has any active keys

    // QK^T for both frags, kf shared
    f32x4 s0[4], s1[4];
    __builtin_amdgcn_s_setprio(1);
#pragma unroll
    for (int nt = 0; nt < 4; nt++) {
      short8 kf0 = *(short8*)&Ks[nt * 16 + l16][quad * 8];
      short8 kf1 = *(short8*)&Ks[nt * 16 + l16][32 + quad * 8];
      f32x4 z1 = {};
      z1 = __builtin_amdgcn_mfma_f32_16x16x32_bf16(kf0, qf[1][0], z1, 0, 0, 0);
      s1[nt] = __builtin_amdgcn_mfma_f32_16x16x32_bf16(kf1, qf[1][1], z1, 0, 0, 0);
      if (a0) {
        f32x4 z0 = {};
        z0 = __builtin_amdgcn_mfma_f32_16x16x32_bf16(kf0, qf[0][0], z0, 0, 0, 0);
        s0[nt] = __builtin_amdgcn_mfma_f32_16x16x32_bf16(kf1, qf[0][1], z0, 0, 0, 0);
      }
    }
    __builtin_amdgcn_s_setprio(0);

    // causal masking (diagonal region only)
    if (k0 + 63 > wrow + 16) {  // frag 1 diagonal
      const int lim1 = wrow + 16 + l16 - k0;
#pragma unroll
      for (int nt = 0; nt < 4; nt++)
#pragma unroll
        for (int r = 0; r < 4; r++)
          if (nt * 16 + quad * 4 + r > lim1) s1[nt][r] = -INFINITY;
    }
    if (a0 && k0 + 63 > wrow) {  // frag 0 diagonal
      const int lim0 = wrow + l16 - k0;
#pragma unroll
      for (int nt = 0; nt < 4; nt++)
#pragma unroll
        for (int r = 0; r < 4; r++)
          if (nt * 16 + quad * 4 + r > lim0) s0[nt][r] = -INFINITY;
    }

    // online softmax: T13 defer-max + ballot-gated shuffles + per-lane partial l
    auto smx = [&](f32x4 (&s)[4], float& mm, float& ll, f32x4 (&oo)[4]) {
      float mx = s[0][0];
#pragma unroll
      for (int nt = 0; nt < 4; nt++)
#pragma unroll
        for (int r = 0; r < 4; r++) mx = fmaxf(mx, s[nt][r]);
      // __all over lane-partials == __all over row-maxima: shuffle-free gate
      if (!__all(mx <= mm + 8.f)) {
        mx = fmaxf(mx, __shfl_xor(mx, 16));
        mx = fmaxf(mx, __shfl_xor(mx, 32));
        float mnew = fmaxf(mm, mx);
        float al = hw_exp2(mm - mnew);  // row-uniform -> valid for per-lane ll
        mm = mnew;
        ll *= al;
#pragma unroll
        for (int dt = 0; dt < 4; dt++)
#pragma unroll
          for (int r = 0; r < 4; r++) oo[dt][r] *= al;
      }
      float psum = 0.f;
#pragma unroll
      for (int nt = 0; nt < 4; nt++) {
        float p0 = hw_exp2(s[nt][0] - mm), p1 = hw_exp2(s[nt][1] - mm);
        float p2 = hw_exp2(s[nt][2] - mm), p3 = hw_exp2(s[nt][3] - mm);
        psum += (p0 + p1) + (p2 + p3);
        unsigned lo = __builtin_amdgcn_perm(fbits(p1), fbits(p0), 0x07060302);
        unsigned hi = __builtin_amdgcn_perm(fbits(p3), fbits(p2), 0x07060302);
        uint2 pk; pk.x = lo; pk.y = hi;
        *(uint2*)&Pw[wave][l16][nt * 16 + quad * 4] = pk;
      }
      ll += psum;  // per-lane partial; quad-reduced in epilogue
    };

    short8 pf00, pf01, pf10, pf11;
    if (a0) {
      smx(s0, m[0], l[0], o[0]);
      pf00 = *(short8*)&Pw[wave][l16][quad * 8];
      pf01 = *(short8*)&Pw[wave][l16][32 + quad * 8];
    }
    smx(s1, m[1], l[1], o[1]);
    pf10 = *(short8*)&Pw[wave][l16][quad * 8];
    pf11 = *(short8*)&Pw[wave][l16][32 + quad * 8];

    // PV for both frags, vf shared
    __builtin_amdgcn_s_setprio(1);
#pragma unroll
    for (int dt = 0; dt < 4; dt++) {
      short8 vf0 = *(short8*)&Vt[dt * 16 + l16][quad * 8];
      short8 vf1 = *(short8*)&Vt[dt * 16 + l16][32 + quad * 8];
      o[1][dt] = __builtin_amdgcn_mfma_f32_16x16x32_bf16(vf0, pf10, o[1][dt], 0, 0, 0);
      o[1][dt] = __builtin_amdgcn_mfma_f32_16x16x32_bf16(vf1, pf11, o[1][dt], 0, 0, 0);
      if (a0) {
        o[0][dt] = __builtin_amdgcn_mfma_f32_16x16x32_bf16(vf0, pf00, o[0][dt], 0, 0, 0);
        o[0][dt] = __builtin_amdgcn_mfma_f32_16x16x32_bf16(vf1, pf01, o[0][dt], 0, 0, 0);
      }
    }
    __builtin_amdgcn_s_setprio(0);
  }

#pragma unroll
  for (int f = 0; f < 2; f++) {
    // quad-reduce the per-lane partial l (once per frag)
    float lr = l[f];
    lr += __shfl_xor(lr, 16);
    lr += __shfl_xor(lr, 32);
    float inv = 1.0f / lr;
    size_t rowg = (size_t)(b * SEQ + wrow + f * 16 + l16) * EMBED + h * HDIM;
#pragma unroll
    for (int dt = 0; dt < 4; dt++) {
      ushort q0 = f2bf(o[f][dt][0] * inv), q1 = f2bf(o[f][dt][1] * inv);
      ushort q2 = f2bf(o[f][dt][2] * inv), q3 = f2bf(o[f][dt][3] * inv);
      uint2 pk;
      pk.x = (unsigned)q0 | ((unsigned)q1 << 16);
      pk.y = (unsigned)q2 | ((unsigned)q3 << 16);
      *(uint2*)&O[rowg + dt * 16 + quad * 4] = pk;
    }
  }
}

// ---------------- launch ----------------
extern "C" void kernel_launch(void* const* d_in, const int* in_sizes, int n_in,
                              void* d_out, int out_size, void* d_ws, size_t ws_size,
                              hipStream_t stream) {
  const float* x = (const float*)d_in[0];
  const float* fcos = (const float*)d_in[1];
  const float* fsin = (const float*)d_in[2];
  const float* wq = (const float*)d_in[3];
  const float* wk = (const float*)d_in[4];
  const float* wv = (const float*)d_in[5];
  const float* wo = (const float*)d_in[6];
  float* out = (float*)d_out;

  const int M = BATCH * SEQ;  // 4096
  ushort* ws = (ushort*)d_ws;
  ushort* xb = ws;
  ushort* wqkv = xb + (size_t)M * EMBED;
  ushort* wob = wqkv + (size_t)QKV_LD * EMBED;
  ushort* QKVb = wob + (size_t)EMBED * EMBED;
  ushort* Ab = QKVb + (size_t)M * QKV_LD;

  dim3 blk(256);
  cvt_all<<<9216, blk, 0, stream>>>(x, wq, wk, wv, wo, xb, wqkv, wob);

  // QKV projection + fused RoPE: 256x256 8-phase GEMM (192 blocks)
  gemm8p<256, 1, ushort><<<dim3(QKV_LD / 256, M / 256), dim3(512), 0, stream>>>(
      xb, wqkv, QKVb, fcos, fsin, M, QKV_LD, EMBED);

  attn_mfma<<<dim3(1024), blk, 0, stream>>>(QKVb, Ab);

  // output projection: 256x128 8-phase GEMM (256 blocks = 1/CU)
  gemm8p<128, 0, float><<<dim3(EMBED / 128, M / 256), dim3(512), 0, stream>>>(
      Ab, wob, out, nullptr, nullptr, M, EMBED, EMBED);
}